// Round 1
// baseline (1901.252 us; speedup 1.0000x reference)
//
#include <hip/hip_runtime.h>
#include <hip/hip_bf16.h>
#include <stdint.h>

typedef __bf16 bf16x8 __attribute__((ext_vector_type(8)));
typedef float  f32x4  __attribute__((ext_vector_type(4)));

#define BATCH 16384
#define HID   1024
#define KK    16
#define NKB   32      // 32 K-blocks of 32
#define BM    128
#define BN    128

// ---- fp32 -> bf16 hi/lo split (RNE) ----
__device__ __forceinline__ unsigned short bf16_rne(float x) {
    uint32_t u = __float_as_uint(x);
    uint32_t r = (u + 0x7fffu + ((u >> 16) & 1u)) >> 16;
    return (unsigned short)r;
}
__device__ __forceinline__ void split2(float x, unsigned short& h, unsigned short& l) {
    h = bf16_rne(x);
    float hf = __uint_as_float(((uint32_t)h) << 16);
    l = bf16_rne(x - hf);   // x - hf is exact in f32
}

// ---- split A: [16384][1024] f32 -> Acomb[kb][b][ hi(32) | lo(32) ] bf16 ----
__global__ __launch_bounds__(256) void k_split_a(const float* __restrict__ A,
                                                 unsigned short* __restrict__ Acomb) {
    uint32_t q   = blockIdx.x * 256u + threadIdx.x;   // 4,194,304 threads, 4 elems each
    uint32_t b   = q >> 8;
    uint32_t rem = q & 255u;
    uint32_t kb  = rem >> 3;
    uint32_t j   = (rem & 7u) * 4u;                   // col within 32-block, x4
    float4 v = *(const float4*)(A + (size_t)b * HID + kb * 32 + j);
    ushort4 hi, lo;
    split2(v.x, hi.x, lo.x); split2(v.y, hi.y, lo.y);
    split2(v.z, hi.z, lo.z); split2(v.w, hi.w, lo.w);
    unsigned short* dst = Acomb + ((size_t)kb * BATCH + b) * 64 + j;
    *(ushort4*)(dst)      = hi;
    *(ushort4*)(dst + 32) = lo;
}

// ---- split+transpose W: [16][1024(h)][1024(d)] f32 -> Wcomb[i][kb][d][ hi(32)|lo(32) ] bf16 ----
__global__ __launch_bounds__(256) void k_split_w(const float* __restrict__ W,
                                                 unsigned short* __restrict__ Wcomb) {
    int bx = blockIdx.x;            // 16*32*16 = 8192 blocks
    int i  = bx >> 9;
    int kb = (bx >> 4) & 31;
    int dt = bx & 15;
    __shared__ float lds[32][65];
    const float* src = W + ((size_t)i * HID + (size_t)kb * 32) * HID + dt * 64;
    int t = threadIdx.x;
    #pragma unroll
    for (int rep = 0; rep < 8; ++rep) {
        int lin = rep * 256 + t;            // 0..2047
        int hl = lin >> 6, dl = lin & 63;
        lds[hl][dl] = src[(size_t)hl * HID + dl];
    }
    __syncthreads();
    #pragma unroll
    for (int rep = 0; rep < 2; ++rep) {
        int cid = rep * 256 + t;            // 0..511 chunks of 8 bf16
        int dl = cid >> 3, qq = cid & 7;
        unsigned short outv[8];
        #pragma unroll
        for (int j = 0; j < 8; ++j) {
            int col = qq * 8 + j;           // 0..63 : hi(h=col) for col<32 else lo(h=col-32)
            float x = (col < 32) ? lds[col][dl] : lds[col - 32][dl];
            unsigned short h, l; split2(x, h, l);
            outv[j] = (col < 32) ? h : l;
        }
        *(uint4*)(Wcomb + ((((size_t)i * NKB + kb) * HID) + dt * 64 + dl) * 64 + qq * 8)
            = *(uint4*)outv;
    }
}

// ---- main bilinear MFMA kernel ----
// score[b,i] += sum_d (sum_h A[b,h] W[i,h,d]) * B[b,d], tile (BM x BN), K-loop of 32.
// 3-product split: Ah*Wh + Ah*Wl + Al*Wh accumulated into same f32 acc.
__global__ __launch_bounds__(256, 2) void k_gemm(const unsigned short* __restrict__ Acomb,
                                                 const unsigned short* __restrict__ Wcomb,
                                                 const float* __restrict__ B,
                                                 float* __restrict__ score) {
    __shared__ __align__(16) unsigned short ldsA[BM * 64];  // 128 rows x 128B (hi32|lo32), XOR-swizzled
    __shared__ __align__(16) unsigned short ldsW[BN * 64];
    const int tid  = threadIdx.x;
    const int lane = tid & 63;
    const int wave = tid >> 6;
    const int wm = wave >> 1, wn = wave & 1;
    const int brow = blockIdx.x * BM;
    const int dcol = blockIdx.y * BN;
    const int i    = blockIdx.z;
    const int l15 = lane & 15, l4 = lane >> 4;

    f32x4 acc[4][4];
    #pragma unroll
    for (int m = 0; m < 4; ++m)
        #pragma unroll
        for (int n = 0; n < 4; ++n)
            acc[m][n] = (f32x4){0.f, 0.f, 0.f, 0.f};

    const unsigned short* baseA = Acomb + (size_t)brow * 64;
    const unsigned short* baseW = Wcomb + ((size_t)i * NKB * HID + dcol) * 64;

    // fragment LDS offsets (ushort units); row stride = 64 ushorts = 128B; 8 chunks of 16B
    int aoff_h[4], aoff_l[4], woff_h[4], woff_l[4];
    #pragma unroll
    for (int m = 0; m < 4; ++m) {
        int row = wm * 64 + m * 16 + l15;
        aoff_h[m] = row * 64 + ((l4    ) ^ (row & 7)) * 8;
        aoff_l[m] = row * 64 + ((l4 + 4) ^ (row & 7)) * 8;
    }
    #pragma unroll
    for (int n = 0; n < 4; ++n) {
        int row = wn * 64 + n * 16 + l15;
        woff_h[n] = row * 64 + ((l4    ) ^ (row & 7)) * 8;
        woff_l[n] = row * 64 + ((l4 + 4) ^ (row & 7)) * 8;
    }

    for (int kb = 0; kb < NKB; ++kb) {
        const unsigned short* srcA = baseA + (size_t)kb * ((size_t)BATCH * 64);
        const unsigned short* srcW = baseW + (size_t)kb * ((size_t)HID * 64);
        #pragma unroll
        for (int r = 0; r < 4; ++r) {
            int c = r * 256 + tid;          // 1024 chunks of 16B per matrix
            int row = c >> 3, sl = c & 7;
            uint4 va = *(const uint4*)(srcA + c * 8);
            uint4 vw = *(const uint4*)(srcW + c * 8);
            int sw = sl ^ (row & 7);        // XOR swizzle (write side)
            *(uint4*)(&ldsA[row * 64 + sw * 8]) = va;
            *(uint4*)(&ldsW[row * 64 + sw * 8]) = vw;
        }
        __syncthreads();
        bf16x8 ah[4], al[4], wh[4], wl[4];
        #pragma unroll
        for (int m = 0; m < 4; ++m) {
            ah[m] = *(const bf16x8*)(&ldsA[aoff_h[m]]);
            al[m] = *(const bf16x8*)(&ldsA[aoff_l[m]]);
        }
        #pragma unroll
        for (int n = 0; n < 4; ++n) {
            wh[n] = *(const bf16x8*)(&ldsW[woff_h[n]]);
            wl[n] = *(const bf16x8*)(&ldsW[woff_l[n]]);
        }
        #pragma unroll
        for (int m = 0; m < 4; ++m)
            #pragma unroll
            for (int n = 0; n < 4; ++n) {
                acc[m][n] = __builtin_amdgcn_mfma_f32_16x16x32_bf16(ah[m], wh[n], acc[m][n], 0, 0, 0);
                acc[m][n] = __builtin_amdgcn_mfma_f32_16x16x32_bf16(ah[m], wl[n], acc[m][n], 0, 0, 0);
                acc[m][n] = __builtin_amdgcn_mfma_f32_16x16x32_bf16(al[m], wh[n], acc[m][n], 0, 0, 0);
            }
        __syncthreads();
    }

    // epilogue: multiply by B and reduce over d (cols), atomicAdd into score[b,i]
    // C/D layout (m89-verified): col = lane&15, row = (lane>>4)*4 + reg
    #pragma unroll
    for (int m = 0; m < 4; ++m) {
        #pragma unroll
        for (int r = 0; r < 4; ++r) {
            int row = brow + wm * 64 + m * 16 + l4 * 4 + r;   // global b
            float s = 0.f;
            #pragma unroll
            for (int n = 0; n < 4; ++n) {
                int col = dcol + wn * 64 + n * 16 + l15;      // global d
                s += acc[m][n][r] * B[(size_t)row * HID + col];
            }
            s += __shfl_xor(s, 1);
            s += __shfl_xor(s, 2);
            s += __shfl_xor(s, 4);
            s += __shfl_xor(s, 8);
            if (l15 == 0) atomicAdd(&score[(size_t)row * KK + i], s);
        }
    }
}

// ---- linear term: lin[b,i] = A[b,:]@Vw[i,:1024] + B[b,:]@Vw[i,1024:] + Vb[i] ----
__global__ __launch_bounds__(256) void k_linear(const float* __restrict__ A,
                                                const float* __restrict__ B,
                                                const float* __restrict__ Vw,
                                                const float* __restrict__ Vb,
                                                float* __restrict__ lin) {
    __shared__ float4 sA[128][9];
    __shared__ float4 sB[128][9];
    __shared__ float4 sVa[16][9];
    __shared__ float4 sVb[16][9];
    const int t = threadIdx.x;
    const int brow = blockIdx.x * 128;
    const int b_loc = t >> 1;
    const int ihalf = t & 1;
    float acc8[8] = {0.f, 0.f, 0.f, 0.f, 0.f, 0.f, 0.f, 0.f};

    for (int hc = 0; hc < HID; hc += 32) {
        __syncthreads();
        #pragma unroll
        for (int rep = 0; rep < 4; ++rep) {
            int idx = rep * 256 + t;         // 1024 float4 per matrix
            int bl = idx >> 3, h4 = idx & 7;
            sA[bl][h4] = *(const float4*)(A + (size_t)(brow + bl) * HID + hc + h4 * 4);
            sB[bl][h4] = *(const float4*)(B + (size_t)(brow + bl) * HID + hc + h4 * 4);
        }
        if (t < 128) {
            int ii = t >> 3, h4 = t & 7;
            sVa[ii][h4] = *(const float4*)(Vw + (size_t)ii * 2048 + hc + h4 * 4);
        } else {
            int tt = t - 128;
            int ii = tt >> 3, h4 = tt & 7;
            sVb[ii][h4] = *(const float4*)(Vw + (size_t)ii * 2048 + 1024 + hc + h4 * 4);
        }
        __syncthreads();
        #pragma unroll
        for (int h4 = 0; h4 < 8; ++h4) {
            float4 a4 = sA[b_loc][h4];
            float4 b4 = sB[b_loc][h4];
            #pragma unroll
            for (int ii = 0; ii < 8; ++ii) {
                int iG = ihalf * 8 + ii;
                float4 va = sVa[iG][h4], vb = sVb[iG][h4];
                acc8[ii] += a4.x * va.x + a4.y * va.y + a4.z * va.z + a4.w * va.w
                          + b4.x * vb.x + b4.y * vb.y + b4.z * vb.z + b4.w * vb.w;
            }
        }
    }
    #pragma unroll
    for (int ii = 0; ii < 8; ++ii) {
        int iG = ihalf * 8 + ii;
        lin[(size_t)(brow + b_loc) * KK + iG] = acc8[ii] + Vb[iG];
    }
}

// ---- finalize: out[b] = out_b + sum_i out_w[i] * tanh(score + lin) ----
__global__ __launch_bounds__(256) void k_final(const float* __restrict__ score,
                                               const float* __restrict__ lin,
                                               const float* __restrict__ out_w,
                                               const float* __restrict__ out_b,
                                               float* __restrict__ out) {
    int b = blockIdx.x * 256 + threadIdx.x;
    float o = out_b[0];
    #pragma unroll
    for (int i = 0; i < KK; ++i)
        o += out_w[i] * tanhf(score[(size_t)b * KK + i] + lin[(size_t)b * KK + i]);
    out[b] = o;
}

extern "C" void kernel_launch(void* const* d_in, const int* in_sizes, int n_in,
                              void* d_out, int out_size, void* d_ws, size_t ws_size,
                              hipStream_t stream) {
    (void)in_sizes; (void)n_in; (void)out_size; (void)ws_size;
    const float* A     = (const float*)d_in[0];
    const float* B     = (const float*)d_in[1];
    const float* W     = (const float*)d_in[2];
    const float* Vw    = (const float*)d_in[3];
    const float* Vb    = (const float*)d_in[4];
    const float* out_w = (const float*)d_in[5];
    const float* out_b = (const float*)d_in[6];
    float* out = (float*)d_out;

    // workspace layout: Acomb 64MiB | Wcomb 64MiB | score 1MiB | lin 1MiB
    unsigned short* Acomb = (unsigned short*)d_ws;
    unsigned short* Wcomb = Acomb + (size_t)NKB * BATCH * 64;
    float* score = (float*)(Wcomb + (size_t)KK * NKB * HID * 64);
    float* lin   = score + (size_t)BATCH * KK;

    hipMemsetAsync(score, 0, (size_t)BATCH * KK * sizeof(float), stream);
    k_split_a<<<dim3(16384), dim3(256), 0, stream>>>(A, Acomb);
    k_split_w<<<dim3(8192), dim3(256), 0, stream>>>(W, Wcomb);
    dim3 g(BATCH / BM, HID / BN, KK);
    k_gemm<<<g, dim3(256), 0, stream>>>(Acomb, Wcomb, B, score);
    k_linear<<<dim3(BATCH / 128), dim3(256), 0, stream>>>(A, B, Vw, Vb, lin);
    k_final<<<dim3(BATCH / 256), dim3(256), 0, stream>>>(score, lin, out_w, out_b, out);
}

// Round 2
// 1647.287 us; speedup vs baseline: 1.1542x; 1.1542x over previous
//
#include <hip/hip_runtime.h>
#include <hip/hip_bf16.h>
#include <stdint.h>

typedef __bf16 bf16x8 __attribute__((ext_vector_type(8)));
typedef float  f32x4  __attribute__((ext_vector_type(4)));
typedef unsigned short ushort_t;

#define BATCH 16384
#define HID   1024
#define KK    16
#define NKB   32      // 32 K-blocks of 32 f32 cols
#define BM    256
#define BN    256
#define BUFS  32768   // ushorts per LDS buffer (A 16384 | W 16384)
#define LDSW_OFF 16384

// ---- fp32 -> bf16 hi/lo split (RNE) ----
__device__ __forceinline__ unsigned short bf16_rne(float x) {
    uint32_t u = __float_as_uint(x);
    uint32_t r = (u + 0x7fffu + ((u >> 16) & 1u)) >> 16;
    return (unsigned short)r;
}
__device__ __forceinline__ void split2(float x, unsigned short& h, unsigned short& l) {
    h = bf16_rne(x);
    float hf = __uint_as_float(((uint32_t)h) << 16);
    l = bf16_rne(x - hf);   // x - hf exact in f32
}

// ---- split A -> Acomb[kb][b][8 chunks of 8 ushorts], chunks PRE-SWIZZLED by (b&7) ----
// logical chunks: 0-3 = hi (k 0..31), 4-7 = lo; stored at position c ^ (b&7)
__global__ __launch_bounds__(256) void k_split_a(const float* __restrict__ A,
                                                 ushort_t* __restrict__ Acomb) {
    uint32_t q   = blockIdx.x * 256u + threadIdx.x;   // 2,097,152 threads
    uint32_t b   = q >> 7;
    uint32_t rem = q & 127u;
    uint32_t kb  = rem >> 2;
    uint32_t cq  = rem & 3u;
    const float* src = A + (size_t)b * HID + kb * 32 + cq * 8;
    float4 v0 = *(const float4*)src;
    float4 v1 = *(const float4*)(src + 4);
    ushort_t h[8], l[8];
    split2(v0.x, h[0], l[0]); split2(v0.y, h[1], l[1]);
    split2(v0.z, h[2], l[2]); split2(v0.w, h[3], l[3]);
    split2(v1.x, h[4], l[4]); split2(v1.y, h[5], l[5]);
    split2(v1.z, h[6], l[6]); split2(v1.w, h[7], l[7]);
    ushort_t* row = Acomb + ((size_t)kb * BATCH + b) * 64;
    uint32_t sw = b & 7u;
    *(uint4*)(row + ((cq      ) ^ sw) * 8) = *(uint4*)h;
    *(uint4*)(row + ((cq + 4u) ^ sw) * 8) = *(uint4*)l;
}

// ---- split+transpose W -> Wcomb[i][kb][d][8 chunks], chunks PRE-SWIZZLED by (d&7) ----
__global__ __launch_bounds__(256) void k_split_w(const float* __restrict__ W,
                                                 ushort_t* __restrict__ Wcomb) {
    int bx = blockIdx.x;            // 16*32*16 = 8192 blocks
    int i  = bx >> 9;
    int kb = (bx >> 4) & 31;
    int dt = bx & 15;
    __shared__ float lds[32][65];
    const float* src = W + ((size_t)i * HID + (size_t)kb * 32) * HID + dt * 64;
    int t = threadIdx.x;
    #pragma unroll
    for (int rep = 0; rep < 8; ++rep) {
        int lin = rep * 256 + t;            // 0..2047
        int hl = lin >> 6, dl = lin & 63;
        lds[hl][dl] = src[(size_t)hl * HID + dl];
    }
    __syncthreads();
    #pragma unroll
    for (int rep = 0; rep < 2; ++rep) {
        int cid = rep * 256 + t;            // 0..511 chunks of 8 ushorts
        int dl = cid >> 3, qq = cid & 7;
        ushort_t outv[8];
        #pragma unroll
        for (int j = 0; j < 8; ++j) {
            int col = qq * 8 + j;           // col<32: hi(h=col); else lo(h=col-32)
            float x = (col < 32) ? lds[col][dl] : lds[col - 32][dl];
            unsigned short h, l; split2(x, h, l);
            outv[j] = (col < 32) ? h : l;
        }
        *(uint4*)(Wcomb + ((((size_t)i * NKB + kb) * HID) + dt * 64 + dl) * 64
                  + (qq ^ (dl & 7)) * 8) = *(uint4*)outv;
    }
}

// ---- main bilinear MFMA kernel: 256x256 tile, 8 waves, 4-phase schedule ----
#define BAR() asm volatile("s_barrier" ::: "memory")
#define GLL(gsrc, dstIdx) \
    __builtin_amdgcn_global_load_lds((const __attribute__((address_space(1))) void*)(gsrc), \
        (__attribute__((address_space(3))) void*)(&smem[(dstIdx)]), 16, 0, 0)

__global__ __launch_bounds__(512, 2) void k_gemm(const ushort_t* __restrict__ Acomb,
                                                 const ushort_t* __restrict__ Wcomb,
                                                 const float* __restrict__ B,
                                                 float* __restrict__ score) {
    __shared__ __align__(16) ushort_t smem[2 * BUFS];   // 128 KiB
    const int tid  = threadIdx.x;
    const int lane = tid & 63;
    const int wave = tid >> 6;
    const int wm = wave >> 2, wn = wave & 3;
    const int l15 = lane & 15, l4 = lane >> 4;
    const int brow = blockIdx.x * BM;
    const int dcol = blockIdx.y * BN;
    const int i    = blockIdx.z;

    f32x4 acc[8][4];
    #pragma unroll
    for (int m = 0; m < 8; ++m)
        #pragma unroll
        for (int n = 0; n < 4; ++n)
            acc[m][n] = (f32x4){0.f, 0.f, 0.f, 0.f};

    // ds-read fragment bases (ushort units, buffer 0); row&7 == l15&7 for all frag rows
    const int csw_hi = ((l4    ) ^ (l15 & 7)) * 8;
    const int csw_lo = ((l4 + 4) ^ (l15 & 7)) * 8;
    const int aoff_hi = (wm * 128 + l15) * 64 + csw_hi;             // + m*1024 + cb
    const int aoff_lo = (wm * 128 + l15) * 64 + csw_lo;
    const int woff_hi = LDSW_OFF + (wn * 64 + l15) * 64 + csw_hi;   // + n*1024 + cb
    const int woff_lo = LDSW_OFF + (wn * 64 + l15) * 64 + csw_lo;

    // staging bases: per-thread global (pre-swizzled layout -> fully linear)
    const ushort_t* gA0 = Acomb + ((size_t)brow + wave * 16) * 64 + lane * 8;
    const ushort_t* gW0 = Wcomb + ((size_t)i * NKB * HID + dcol + wave * 16) * 64 + lane * 8;
    const int sdst = wave * 1024;    // wave-uniform LDS dest (ushorts)

#define STAGE_A(c, t1, h) do { \
    const ushort_t* g_ = gA0 + ((size_t)(t1) * BATCH + (h) * 128) * 64; \
    GLL(g_,       (c) * BUFS + (h) * 8192 + sdst); \
    GLL(g_ + 512, (c) * BUFS + (h) * 8192 + sdst + 512); \
  } while (0)
#define STAGE_W(c, t1, h) do { \
    const ushort_t* g_ = gW0 + ((size_t)(t1) * HID + (h) * 128) * 64; \
    GLL(g_,       (c) * BUFS + LDSW_OFF + (h) * 8192 + sdst); \
    GLL(g_ + 512, (c) * BUFS + LDSW_OFF + (h) * 8192 + sdst + 512); \
  } while (0)

    bf16x8 ah[4], al[4], wh[4], wl[4];
#define RD_W(n, cb) do { \
    wh[n] = *(const bf16x8*)(&smem[(cb) + woff_hi + (n) * 1024]); \
    wl[n] = *(const bf16x8*)(&smem[(cb) + woff_lo + (n) * 1024]); } while (0)
#define RD_A(m, slot, cb) do { \
    ah[slot] = *(const bf16x8*)(&smem[(cb) + aoff_hi + (m) * 1024]); \
    al[slot] = *(const bf16x8*)(&smem[(cb) + aoff_lo + (m) * 1024]); } while (0)

#define MFMA_Q(MB, NB) do { \
    __builtin_amdgcn_s_setprio(1); \
    _Pragma("unroll") \
    for (int mm = 0; mm < 4; ++mm) { \
      _Pragma("unroll") \
      for (int nn = 0; nn < 2; ++nn) \
        acc[(MB)+mm][(NB)+nn] = __builtin_amdgcn_mfma_f32_16x16x32_bf16(ah[mm], wh[(NB)+nn], acc[(MB)+mm][(NB)+nn], 0, 0, 0); } \
    _Pragma("unroll") \
    for (int mm = 0; mm < 4; ++mm) { \
      _Pragma("unroll") \
      for (int nn = 0; nn < 2; ++nn) \
        acc[(MB)+mm][(NB)+nn] = __builtin_amdgcn_mfma_f32_16x16x32_bf16(ah[mm], wl[(NB)+nn], acc[(MB)+mm][(NB)+nn], 0, 0, 0); } \
    _Pragma("unroll") \
    for (int mm = 0; mm < 4; ++mm) { \
      _Pragma("unroll") \
      for (int nn = 0; nn < 2; ++nn) \
        acc[(MB)+mm][(NB)+nn] = __builtin_amdgcn_mfma_f32_16x16x32_bf16(al[mm], wh[(NB)+nn], acc[(MB)+mm][(NB)+nn], 0, 0, 0); } \
    __builtin_amdgcn_s_setprio(0); \
  } while (0)

#define TILE_BODY(c, t, DOSTAGE) do { \
    const int cb = (c) * BUFS; \
    /* region 0: stage A-halves of t+1, read w01 + a03 */ \
    if (DOSTAGE) { STAGE_A((c) ^ 1, (t) + 1, 0); STAGE_A((c) ^ 1, (t) + 1, 1); } \
    RD_W(0, cb); RD_W(1, cb); \
    RD_A(0, 0, cb); RD_A(1, 1, cb); RD_A(2, 2, cb); RD_A(3, 3, cb); \
    BAR(); \
    MFMA_Q(0, 0); \
    BAR(); \
    /* region 1: stage W-halves of t+1, read w23 */ \
    if (DOSTAGE) { STAGE_W((c) ^ 1, (t) + 1, 0); STAGE_W((c) ^ 1, (t) + 1, 1); } \
    RD_W(2, cb); RD_W(3, cb); \
    BAR(); \
    MFMA_Q(0, 2); \
    BAR(); \
    /* region 2: read a47 */ \
    RD_A(4, 0, cb); RD_A(5, 1, cb); RD_A(6, 2, cb); RD_A(7, 3, cb); \
    BAR(); \
    MFMA_Q(4, 0); \
    BAR(); \
    /* region 3: pure MFMA, then drain staging for next tile */ \
    MFMA_Q(4, 2); \
    __syncthreads(); \
  } while (0)

    // prologue: stage tile 0, drain
    STAGE_A(0, 0, 0); STAGE_A(0, 0, 1);
    STAGE_W(0, 0, 0); STAGE_W(0, 0, 1);
    __syncthreads();

    int cur = 0;
    for (int t = 0; t < NKB - 1; ++t) {
        TILE_BODY(cur, t, 1);
        cur ^= 1;
    }
    TILE_BODY(cur, NKB - 1, 0);

    // epilogue: multiply by B, reduce over d (cols), atomicAdd into score[b,i]
    #pragma unroll
    for (int m = 0; m < 8; ++m) {
        #pragma unroll
        for (int r = 0; r < 4; ++r) {
            int row = brow + wm * 128 + m * 16 + l4 * 4 + r;   // global b
            const float* Brow = B + (size_t)row * HID + dcol + wn * 64 + l15;
            float s = acc[m][0][r] * Brow[0]
                    + acc[m][1][r] * Brow[16]
                    + acc[m][2][r] * Brow[32]
                    + acc[m][3][r] * Brow[48];
            s += __shfl_xor(s, 1);
            s += __shfl_xor(s, 2);
            s += __shfl_xor(s, 4);
            s += __shfl_xor(s, 8);
            if (l15 == 0) atomicAdd(&score[(size_t)row * KK + i], s);
        }
    }
}

// ---- linear term ----
__global__ __launch_bounds__(256) void k_linear(const float* __restrict__ A,
                                                const float* __restrict__ B,
                                                const float* __restrict__ Vw,
                                                const float* __restrict__ Vb,
                                                float* __restrict__ lin) {
    __shared__ float4 sA[128][9];
    __shared__ float4 sB[128][9];
    __shared__ float4 sVa[16][9];
    __shared__ float4 sVb[16][9];
    const int t = threadIdx.x;
    const int brow = blockIdx.x * 128;
    const int b_loc = t >> 1;
    const int ihalf = t & 1;
    float acc8[8] = {0.f, 0.f, 0.f, 0.f, 0.f, 0.f, 0.f, 0.f};

    for (int hc = 0; hc < HID; hc += 32) {
        __syncthreads();
        #pragma unroll
        for (int rep = 0; rep < 4; ++rep) {
            int idx = rep * 256 + t;
            int bl = idx >> 3, h4 = idx & 7;
            sA[bl][h4] = *(const float4*)(A + (size_t)(brow + bl) * HID + hc + h4 * 4);
            sB[bl][h4] = *(const float4*)(B + (size_t)(brow + bl) * HID + hc + h4 * 4);
        }
        if (t < 128) {
            int ii = t >> 3, h4 = t & 7;
            sVa[ii][h4] = *(const float4*)(Vw + (size_t)ii * 2048 + hc + h4 * 4);
        } else {
            int tt = t - 128;
            int ii = tt >> 3, h4 = tt & 7;
            sVb[ii][h4] = *(const float4*)(Vw + (size_t)ii * 2048 + 1024 + hc + h4 * 4);
        }
        __syncthreads();
        #pragma unroll
        for (int h4 = 0; h4 < 8; ++h4) {
            float4 a4 = sA[b_loc][h4];
            float4 b4 = sB[b_loc][h4];
            #pragma unroll
            for (int ii = 0; ii < 8; ++ii) {
                int iG = ihalf * 8 + ii;
                float4 va = sVa[iG][h4], vb = sVb[iG][h4];
                acc8[ii] += a4.x * va.x + a4.y * va.y + a4.z * va.z + a4.w * va.w
                          + b4.x * vb.x + b4.y * vb.y + b4.z * vb.z + b4.w * vb.w;
            }
        }
    }
    #pragma unroll
    for (int ii = 0; ii < 8; ++ii) {
        int iG = ihalf * 8 + ii;
        lin[(size_t)(brow + b_loc) * KK + iG] = acc8[ii] + Vb[iG];
    }
}

// ---- finalize ----
__global__ __launch_bounds__(256) void k_final(const float* __restrict__ score,
                                               const float* __restrict__ lin,
                                               const float* __restrict__ out_w,
                                               const float* __restrict__ out_b,
                                               float* __restrict__ out) {
    int b = blockIdx.x * 256 + threadIdx.x;
    float o = out_b[0];
    #pragma unroll
    for (int i = 0; i < KK; ++i)
        o += out_w[i] * tanhf(score[(size_t)b * KK + i] + lin[(size_t)b * KK + i]);
    out[b] = o;
}

extern "C" void kernel_launch(void* const* d_in, const int* in_sizes, int n_in,
                              void* d_out, int out_size, void* d_ws, size_t ws_size,
                              hipStream_t stream) {
    (void)in_sizes; (void)n_in; (void)out_size; (void)ws_size;
    const float* A     = (const float*)d_in[0];
    const float* B     = (const float*)d_in[1];
    const float* W     = (const float*)d_in[2];
    const float* Vw    = (const float*)d_in[3];
    const float* Vb    = (const float*)d_in[4];
    const float* out_w = (const float*)d_in[5];
    const float* out_b = (const float*)d_in[6];
    float* out = (float*)d_out;

    // workspace: Acomb 64MiB | Wcomb 64MiB | score 1MiB | lin 1MiB
    ushort_t* Acomb = (ushort_t*)d_ws;
    ushort_t* Wcomb = Acomb + (size_t)NKB * BATCH * 64;
    float* score = (float*)(Wcomb + (size_t)KK * NKB * HID * 64);
    float* lin   = score + (size_t)BATCH * KK;

    hipMemsetAsync(score, 0, (size_t)BATCH * KK * sizeof(float), stream);
    k_split_a<<<dim3(8192), dim3(256), 0, stream>>>(A, Acomb);
    k_split_w<<<dim3(8192), dim3(256), 0, stream>>>(W, Wcomb);
    k_gemm<<<dim3(BATCH / BM, HID / BN, KK), dim3(512), 0, stream>>>(Acomb, Wcomb, B, score);
    k_linear<<<dim3(BATCH / 128), dim3(256), 0, stream>>>(A, B, Vw, Vb, lin);
    k_final<<<dim3(BATCH / 256), dim3(256), 0, stream>>>(score, lin, out_w, out_b, out);
}